// Round 9
// baseline (32.119 us; speedup 1.0000x reference)
//
#include <hip/hip_runtime.h>
#include <hip/hip_bf16.h>

// Problem constants (from reference setup_inputs): emission [B, T, V] float32
#define CTC_B 64
#define CTC_T 8192
#define CTC_V 32
#define BLANK 0

// ---------------------------------------------------------------------------
// MEASUREMENT ROUND: identical to R8 (best, 21.25 us) except the argmax
// kernel is launched TWICE (idempotent). dur - 21.25 = marginal cost of one
// steady-state argmax dispatch (incl. node overhead). Attribution decides
// whether to declare roofline or attack the overhead next round.
// ---------------------------------------------------------------------------

// ---------------------------------------------------------------------------
// Kernel 1: argmax over labels. 4 lanes per (b,t) row; each lane loads TWO
// independent float4s -> 2-deep load ILP, 16 rows per wave, 2 shuffle rounds.
// First-occurrence tie-break: in-lane indices ascending with strict '>',
// cross-lane reduce prefers the smaller index on exact float equality.
// ---------------------------------------------------------------------------
__global__ __launch_bounds__(256) void ctc_argmax_kernel(
    const float* __restrict__ em, unsigned char* __restrict__ idx) {
    int tid = blockIdx.x * blockDim.x + threadIdx.x;   // 4 threads per row
    int row = tid >> 2;
    int sub = tid & 3;
    const float4* p = reinterpret_cast<const float4*>(em) + (size_t)row * 8 + sub;
    float4 a = p[0];   // covers elements 4*sub   .. 4*sub+3
    float4 b = p[4];   // covers elements 16+4*sub .. 16+4*sub+3
    const int b1 = sub * 4, b2 = 16 + sub * 4;

    float best = a.x; int bi = b1;
    if (a.y > best) { best = a.y; bi = b1 + 1; }
    if (a.z > best) { best = a.z; bi = b1 + 2; }
    if (a.w > best) { best = a.w; bi = b1 + 3; }
    if (b.x > best) { best = b.x; bi = b2;     }
    if (b.y > best) { best = b.y; bi = b2 + 1; }
    if (b.z > best) { best = b.z; bi = b2 + 2; }
    if (b.w > best) { best = b.w; bi = b2 + 3; }

    // reduce across the 4-lane group (xor masks 1,2 stay in-group)
#pragma unroll
    for (int m = 1; m < 4; m <<= 1) {
        float ob = __shfl_xor(best, m, 64);
        int   oi = __shfl_xor(bi,   m, 64);
        if (ob > best || (ob == best && oi < bi)) { best = ob; bi = oi; }
    }
    if (sub == 0) idx[row] = (unsigned char)bi;   // 16 consecutive bytes/wave
}

// ---------------------------------------------------------------------------
// SWAR: high bit of each byte set iff that byte of x is nonzero.
// ---------------------------------------------------------------------------
__device__ __forceinline__ unsigned long long nzmask(unsigned long long x) {
    return (x | ((x & 0x7f7f7f7f7f7f7f7fULL) + 0x7f7f7f7f7f7f7f7fULL))
           & 0x8080808080808080ULL;
}

// ---------------------------------------------------------------------------
// Kernel 2 (fused colkeep + compact): one block of 1024 threads per batch
// row; each thread owns 8 CONSECUTIVE columns (one u64 byte-vector). Single
// pass, single barrier.
// ---------------------------------------------------------------------------
__global__ __launch_bounds__(1024) void ctc_compact_kernel(
    const unsigned char* __restrict__ idx,
    int* __restrict__ btokens, int* __restrict__ lens) {
    const int b   = blockIdx.x;
    const int tid = threadIdx.x;
    const int t8  = tid * 8;                     // first column this thread owns
    const unsigned char* row = idx + (size_t)b * CTC_T;
    int* orow = btokens + (size_t)b * CTC_T;

    __shared__ int s_wsum[16];
    const int lane = tid & 63;
    const int wid  = tid >> 6;

    // --- load own 8 values + boundary byte, and dedup rows 0,1 ---
    const unsigned long long xv = *reinterpret_cast<const unsigned long long*>(row + t8);
    const unsigned char* r0 = idx;               // batch row 0
    const unsigned char* r1 = idx + CTC_T;       // batch row 1
    unsigned long long x0 = *reinterpret_cast<const unsigned long long*>(r0 + t8);
    unsigned long long x1 = *reinterpret_cast<const unsigned long long*>(r1 + t8);
    unsigned char p0 = (t8 == 0) ? (unsigned char)0 : r0[t8 - 1];
    unsigned char p1 = (t8 == 0) ? (unsigned char)0 : r1[t8 - 1];

    // colkeep high-bit mask: byte j <-> column t8+j ; prev column = byte j-1
    unsigned long long hk = nzmask(x0 ^ ((x0 << 8) | (unsigned long long)p0))
                          | nzmask(x1 ^ ((x1 << 8) | (unsigned long long)p1));
    if (t8 == 0) hk |= 0x80ULL;                  // col_keep[0] = 1 always

    unsigned long long und = ~hk & 0x8080808080808080ULL;
    for (int bb = 2; bb < CTC_B && und; ++bb) {
        const unsigned char* rb = idx + (size_t)bb * CTC_T;
        unsigned long long xb = *reinterpret_cast<const unsigned long long*>(rb + t8);
        unsigned char pb = (t8 == 0) ? (unsigned char)0 : rb[t8 - 1];
        hk |= nzmask(xb ^ ((xb << 8) | (unsigned long long)pb));
        und = ~hk & 0x8080808080808080ULL;
    }

    // keep = col_keep & (value != BLANK)   (BLANK==0 -> nonzero byte)
    const unsigned long long keep_hi = hk & nzmask(xv);
    const int c = __popcll(keep_hi);

    // --- block exclusive scan of per-thread counts ---
    int scan = c;
#pragma unroll
    for (int m = 1; m < 64; m <<= 1) {
        int o = __shfl_up(scan, m, 64);
        if (lane >= m) scan += o;
    }
    if (lane == 63) s_wsum[wid] = scan;          // wave total (inclusive of last)
    __syncthreads();

    int woff = 0, total = 0;
#pragma unroll
    for (int w = 0; w < 16; ++w) {
        int x = s_wsum[w];
        if (w < wid) woff += x;
        total += x;
    }
    int pos = woff + (scan - c);                 // global exclusive prefix

    // --- scatter kept tokens (consecutive per thread) ---
#pragma unroll
    for (int j = 0; j < 8; ++j) {
        if (keep_hi & (0x80ULL << (8 * j))) {
            orow[pos++] = (int)((xv >> (8 * j)) & 0xffULL);
        }
    }

    // --- tail zero-fill (int4-vectorized) + lens ---
    int vstart = (total + 3) & ~3;               // 16B-aligned fill start
    if (tid < vstart - total) orow[total + tid] = BLANK;
    int4* vout = reinterpret_cast<int4*>(orow + vstart);
    const int nvec = (CTC_T - vstart) >> 2;
    const int4 z = make_int4(BLANK, BLANK, BLANK, BLANK);
    for (int i = tid; i < nvec; i += 1024) vout[i] = z;
    if (tid == 0) lens[b] = total;
}

// ---------------------------------------------------------------------------
extern "C" void kernel_launch(void* const* d_in, const int* in_sizes, int n_in,
                              void* d_out, int out_size, void* d_ws, size_t ws_size,
                              hipStream_t stream) {
    const float* emission = (const float*)d_in[0];
    int* out = (int*)d_out;                 // [B*T btokens][B lens], int32
    int* btokens = out;
    int* lens = out + (size_t)CTC_B * CTC_T;

    unsigned char* idx = (unsigned char*)d_ws;   // B*T bytes

    const int total_threads = CTC_B * CTC_T * 4; // 4 lanes per row
    // PROBE: argmax launched twice (idempotent). Marginal dur = t_argmax.
    ctc_argmax_kernel<<<total_threads / 256, 256, 0, stream>>>(emission, idx);
    ctc_argmax_kernel<<<total_threads / 256, 256, 0, stream>>>(emission, idx);
    ctc_compact_kernel<<<CTC_B, 1024, 0, stream>>>(idx, btokens, lens);
}

// Round 10
// 21.181 us; speedup vs baseline: 1.5164x; 1.5164x over previous
//
#include <hip/hip_runtime.h>
#include <hip/hip_bf16.h>

// Problem constants (from reference setup_inputs): emission [B, T, V] float32
#define CTC_B 64
#define CTC_T 8192
#define CTC_V 32
#define BLANK 0

// ---------------------------------------------------------------------------
// Kernel 1: argmax over labels. 4 lanes per (b,t) row; each lane loads TWO
// independent float4s (elements [4s,4s+4) and [16+4s,16+4s+4)).
// R10 change: value-max via v_max3-shaped fmaxf tree + equality index scan
// (~26 VALU/thread vs ~40 for the dual compare-select chains).
// Semantics: max is commutative (no NaNs in input); index = first e in
// global element order with v[e] == groupmax -> exact first-occurrence
// tie-break, identical to jnp.argmax.
// ---------------------------------------------------------------------------
__global__ __launch_bounds__(256) void ctc_argmax_kernel(
    const float* __restrict__ em, unsigned char* __restrict__ idx) {
    int tid = blockIdx.x * blockDim.x + threadIdx.x;   // 4 threads per row
    int row = tid >> 2;
    int sub = tid & 3;
    const float4* p = reinterpret_cast<const float4*>(em) + (size_t)row * 8 + sub;
    float4 a = p[0];   // covers elements 4*sub    .. 4*sub+3
    float4 b = p[4];   // covers elements 16+4*sub .. 16+4*sub+3

    // in-lane max of 8 values: v_max3-friendly tree (4 ops)
    float m0 = __builtin_fmaxf(__builtin_fmaxf(a.x, a.y), a.z);
    float m1 = __builtin_fmaxf(__builtin_fmaxf(a.w, b.x), b.y);
    float m2 = __builtin_fmaxf(b.z, b.w);
    float g  = __builtin_fmaxf(__builtin_fmaxf(m0, m1), m2);

    // group max across the 4-lane group (xor masks 1,2 stay in-group)
    g = __builtin_fmaxf(g, __shfl_xor(g, 1, 64));
    g = __builtin_fmaxf(g, __shfl_xor(g, 2, 64));

    // local first-match index in global element order (descending scan ->
    // earliest e wins); sentinel 255 if this lane has no match.
    const int e1 = sub * 4, e2 = 16 + sub * 4;
    int li = 255;
    if (b.w == g) li = e2 + 3;
    if (b.z == g) li = e2 + 2;
    if (b.y == g) li = e2 + 1;
    if (b.x == g) li = e2;
    if (a.w == g) li = e1 + 3;
    if (a.z == g) li = e1 + 2;
    if (a.y == g) li = e1 + 1;
    if (a.x == g) li = e1;

    // group min-index (at least one lane has a match)
    li = min(li, __shfl_xor(li, 1, 64));
    li = min(li, __shfl_xor(li, 2, 64));

    if (sub == 0) idx[row] = (unsigned char)li;   // 16 consecutive bytes/wave
}

// ---------------------------------------------------------------------------
// SWAR: high bit of each byte set iff that byte of x is nonzero.
// ---------------------------------------------------------------------------
__device__ __forceinline__ unsigned long long nzmask(unsigned long long x) {
    return (x | ((x & 0x7f7f7f7f7f7f7f7fULL) + 0x7f7f7f7f7f7f7f7fULL))
           & 0x8080808080808080ULL;
}

// ---------------------------------------------------------------------------
// Kernel 2 (fused colkeep + compact): one block of 1024 threads per batch
// row; each thread owns 8 CONSECUTIVE columns (one u64 byte-vector). Single
// pass, single barrier. (Unchanged from the 21.25 us best.)
// ---------------------------------------------------------------------------
__global__ __launch_bounds__(1024) void ctc_compact_kernel(
    const unsigned char* __restrict__ idx,
    int* __restrict__ btokens, int* __restrict__ lens) {
    const int b   = blockIdx.x;
    const int tid = threadIdx.x;
    const int t8  = tid * 8;                     // first column this thread owns
    const unsigned char* row = idx + (size_t)b * CTC_T;
    int* orow = btokens + (size_t)b * CTC_T;

    __shared__ int s_wsum[16];
    const int lane = tid & 63;
    const int wid  = tid >> 6;

    // --- load own 8 values + boundary byte, and dedup rows 0,1 ---
    const unsigned long long xv = *reinterpret_cast<const unsigned long long*>(row + t8);
    const unsigned char* r0 = idx;               // batch row 0
    const unsigned char* r1 = idx + CTC_T;       // batch row 1
    unsigned long long x0 = *reinterpret_cast<const unsigned long long*>(r0 + t8);
    unsigned long long x1 = *reinterpret_cast<const unsigned long long*>(r1 + t8);
    unsigned char p0 = (t8 == 0) ? (unsigned char)0 : r0[t8 - 1];
    unsigned char p1 = (t8 == 0) ? (unsigned char)0 : r1[t8 - 1];

    // colkeep high-bit mask: byte j <-> column t8+j ; prev column = byte j-1
    unsigned long long hk = nzmask(x0 ^ ((x0 << 8) | (unsigned long long)p0))
                          | nzmask(x1 ^ ((x1 << 8) | (unsigned long long)p1));
    if (t8 == 0) hk |= 0x80ULL;                  // col_keep[0] = 1 always

    unsigned long long und = ~hk & 0x8080808080808080ULL;
    for (int bb = 2; bb < CTC_B && und; ++bb) {
        const unsigned char* rb = idx + (size_t)bb * CTC_T;
        unsigned long long xb = *reinterpret_cast<const unsigned long long*>(rb + t8);
        unsigned char pb = (t8 == 0) ? (unsigned char)0 : rb[t8 - 1];
        hk |= nzmask(xb ^ ((xb << 8) | (unsigned long long)pb));
        und = ~hk & 0x8080808080808080ULL;
    }

    // keep = col_keep & (value != BLANK)   (BLANK==0 -> nonzero byte)
    const unsigned long long keep_hi = hk & nzmask(xv);
    const int c = __popcll(keep_hi);

    // --- block exclusive scan of per-thread counts ---
    int scan = c;
#pragma unroll
    for (int m = 1; m < 64; m <<= 1) {
        int o = __shfl_up(scan, m, 64);
        if (lane >= m) scan += o;
    }
    if (lane == 63) s_wsum[wid] = scan;          // wave total (inclusive of last)
    __syncthreads();

    int woff = 0, total = 0;
#pragma unroll
    for (int w = 0; w < 16; ++w) {
        int x = s_wsum[w];
        if (w < wid) woff += x;
        total += x;
    }
    int pos = woff + (scan - c);                 // global exclusive prefix

    // --- scatter kept tokens (consecutive per thread) ---
#pragma unroll
    for (int j = 0; j < 8; ++j) {
        if (keep_hi & (0x80ULL << (8 * j))) {
            orow[pos++] = (int)((xv >> (8 * j)) & 0xffULL);
        }
    }

    // --- tail zero-fill (int4-vectorized) + lens ---
    int vstart = (total + 3) & ~3;               // 16B-aligned fill start
    if (tid < vstart - total) orow[total + tid] = BLANK;
    int4* vout = reinterpret_cast<int4*>(orow + vstart);
    const int nvec = (CTC_T - vstart) >> 2;
    const int4 z = make_int4(BLANK, BLANK, BLANK, BLANK);
    for (int i = tid; i < nvec; i += 1024) vout[i] = z;
    if (tid == 0) lens[b] = total;
}

// ---------------------------------------------------------------------------
extern "C" void kernel_launch(void* const* d_in, const int* in_sizes, int n_in,
                              void* d_out, int out_size, void* d_ws, size_t ws_size,
                              hipStream_t stream) {
    const float* emission = (const float*)d_in[0];
    int* out = (int*)d_out;                 // [B*T btokens][B lens], int32
    int* btokens = out;
    int* lens = out + (size_t)CTC_B * CTC_T;

    unsigned char* idx = (unsigned char*)d_ws;   // B*T bytes

    const int total_threads = CTC_B * CTC_T * 4; // 4 lanes per row
    ctc_argmax_kernel<<<total_threads / 256, 256, 0, stream>>>(emission, idx);
    ctc_compact_kernel<<<CTC_B, 1024, 0, stream>>>(idx, btokens, lens);
}